// Round 8
// baseline (502.427 us; speedup 1.0000x reference)
//
#include <hip/hip_runtime.h>
#include <math.h>
#include <stdint.h>

typedef unsigned int u32;
typedef unsigned long long u64;

#define BLOCK 256
#define ITEMS 8
#define CHUNK (BLOCK * ITEMS)  // 2048 elements per block

// ---------------------------------------------------------------------------
// Async global->LDS (gfx950): dest = wave-uniform LDS base + lane*16;
// src is per-lane. size must be a literal (16B -> global_load_lds_dwordx4).
// ---------------------------------------------------------------------------
__device__ __forceinline__ void stage16(const float4* g, float4* l) {
    __builtin_amdgcn_global_load_lds(
        (const __attribute__((address_space(1))) void*)g,
        (__attribute__((address_space(3))) void*)l, 16, 0, 0);
}

// ---------------------------------------------------------------------------
// Pass 1: per-block class histograms + 2-bit packed labels (one u32 per
// (block,tid), 16 bits used) in sort's exact access pattern.
// Zero-inits loss accumulator + done ticket.
// ---------------------------------------------------------------------------
__global__ void __launch_bounds__(BLOCK)
hist_kernel(const int* __restrict__ labels, int N,
            u32* __restrict__ hist, u32* __restrict__ plab,
            double* __restrict__ acc, u32* __restrict__ done) {
    __shared__ u32 s_cnt[4][4];  // [wave][class]
    int tid = threadIdx.x;
    int lane = tid & 63;
    int wave = tid >> 6;
    int base = blockIdx.x * CHUNK;
    u32 packed = 0;
    u32 c0 = 0, c1 = 0, c2 = 0, c3 = 0;
#pragma unroll
    for (int j = 0; j < ITEMS; ++j) {
        int idx = base + j * BLOCK + tid;
        bool valid = idx < N;
        int l = valid ? labels[idx] : 0;
        packed |= (u32)l << (2 * j);
        c0 += (valid && l == 0);
        c1 += (valid && l == 1);
        c2 += (valid && l == 2);
        c3 += (valid && l == 3);
    }
    plab[blockIdx.x * BLOCK + tid] = packed;
#pragma unroll
    for (int off = 32; off > 0; off >>= 1) {
        c0 += (u32)__shfl_down((int)c0, off, 64);
        c1 += (u32)__shfl_down((int)c1, off, 64);
        c2 += (u32)__shfl_down((int)c2, off, 64);
        c3 += (u32)__shfl_down((int)c3, off, 64);
    }
    if (lane == 0) {
        s_cnt[wave][0] = c0; s_cnt[wave][1] = c1;
        s_cnt[wave][2] = c2; s_cnt[wave][3] = c3;
    }
    __syncthreads();
    if (tid < 4)
        hist[blockIdx.x * 4 + tid] =
            s_cnt[0][tid] + s_cnt[1][tid] + s_cnt[2][tid] + s_cnt[3][tid];
    if (blockIdx.x == 0 && tid == 0) { *acc = 0.0; *done = 0u; }
}

// ---------------------------------------------------------------------------
// Pass 2: async-stage the 32KB data tile into LDS (no VGPR cost -> deep MLP
// without fighting the allocator's 64-VGPR budget), overlap the rank phase
// (ballots + block scan + L2-hot global prefix) with the DMA, then process
// from LDS: margin-adjust + scatter + loss. Fused analytic label write and
// done-ticket loss finalize (no 3rd dispatch). 4 blocks/CU (33.5KB LDS) x
// 32KB staged = 128KB in flight per CU -> read stream saturates HBM.
// ---------------------------------------------------------------------------
struct SortShared {
    float4 data[ITEMS * BLOCK];  // 32 KB staged tile (linear [j][tid])
    u32 s_pre[ITEMS][4][4];      // [iter][wave][class] -> excl prefix
    u32 s_red[4][8];             // [wave][bef.xyzw, tot.xyzw]
    u32 s_bc[8];                 // sb0..sb3, cb1..cb3
    double s_w[4];
};

__device__ __forceinline__ void
global_prefix(SortShared& sh, const u32* __restrict__ hist, int nb, int myb) {
    int tid = threadIdx.x;
    int lane = tid & 63;
    int wave = tid >> 6;
    uint4 bef = make_uint4(0, 0, 0, 0), tot = make_uint4(0, 0, 0, 0);
    const uint4* h4 = (const uint4*)hist;
    for (int bb = tid; bb < nb; bb += BLOCK) {
        uint4 h = h4[bb];
        tot.x += h.x; tot.y += h.y; tot.z += h.z; tot.w += h.w;
        if (bb < myb) {
            bef.x += h.x; bef.y += h.y; bef.z += h.z; bef.w += h.w;
        }
    }
#pragma unroll
    for (int off = 32; off > 0; off >>= 1) {
        bef.x += (u32)__shfl_down((int)bef.x, off, 64);
        bef.y += (u32)__shfl_down((int)bef.y, off, 64);
        bef.z += (u32)__shfl_down((int)bef.z, off, 64);
        bef.w += (u32)__shfl_down((int)bef.w, off, 64);
        tot.x += (u32)__shfl_down((int)tot.x, off, 64);
        tot.y += (u32)__shfl_down((int)tot.y, off, 64);
        tot.z += (u32)__shfl_down((int)tot.z, off, 64);
        tot.w += (u32)__shfl_down((int)tot.w, off, 64);
    }
    if (lane == 0) {
        sh.s_red[wave][0] = bef.x; sh.s_red[wave][1] = bef.y;
        sh.s_red[wave][2] = bef.z; sh.s_red[wave][3] = bef.w;
        sh.s_red[wave][4] = tot.x; sh.s_red[wave][5] = tot.y;
        sh.s_red[wave][6] = tot.z; sh.s_red[wave][7] = tot.w;
    }
    __syncthreads();
    if (tid == 0) {
        u32 B0 = sh.s_red[0][0] + sh.s_red[1][0] + sh.s_red[2][0] + sh.s_red[3][0];
        u32 B1 = sh.s_red[0][1] + sh.s_red[1][1] + sh.s_red[2][1] + sh.s_red[3][1];
        u32 B2 = sh.s_red[0][2] + sh.s_red[1][2] + sh.s_red[2][2] + sh.s_red[3][2];
        u32 B3 = sh.s_red[0][3] + sh.s_red[1][3] + sh.s_red[2][3] + sh.s_red[3][3];
        u32 T0 = sh.s_red[0][4] + sh.s_red[1][4] + sh.s_red[2][4] + sh.s_red[3][4];
        u32 T1 = sh.s_red[0][5] + sh.s_red[1][5] + sh.s_red[2][5] + sh.s_red[3][5];
        u32 T2 = sh.s_red[0][6] + sh.s_red[1][6] + sh.s_red[2][6] + sh.s_red[3][6];
        u32 cb1 = T0, cb2 = T0 + T1, cb3 = T0 + T1 + T2;
        sh.s_bc[0] = B0;       sh.s_bc[1] = cb1 + B1;
        sh.s_bc[2] = cb2 + B2; sh.s_bc[3] = cb3 + B3;
        sh.s_bc[4] = cb1; sh.s_bc[5] = cb2; sh.s_bc[6] = cb3;
    }
    __syncthreads();
}

template <bool FULL>
__device__ __forceinline__ void
sort_body(SortShared& sh, const float4* __restrict__ data,
          const u32* __restrict__ plab, int N, int nb,
          const u32* __restrict__ hist, float4* __restrict__ out_data,
          float* __restrict__ out_label, double* __restrict__ acc,
          u32* __restrict__ done, float* __restrict__ out_loss) {
    int tid = threadIdx.x;
    int lane = tid & 63;
    int wave = tid >> 6;
    int base = blockIdx.x * CHUNK;

    // --- One dword: all 8 labels for this thread (issued first).
    u32 packed = plab[blockIdx.x * BLOCK + tid];
    u32 vmask;
    if (FULL) {
        vmask = 0xFFu;
    } else {
        int rem = N - base - tid;
        vmask = 0;
#pragma unroll
        for (int j = 0; j < ITEMS; ++j)
            vmask |= (u32)(j * BLOCK < rem) << j;
    }

    // --- Async-stage the whole data tile (FULL blocks only). Fire-and-forget:
    //     8 DMA issues/thread, zero VGPR. Drained by the vmcnt(0) the compiler
    //     emits before the first __syncthreads below.
    if (FULL) {
#pragma unroll
        for (int j = 0; j < ITEMS; ++j) {
            stage16(&data[base + j * BLOCK + wave * 64 + lane],
                    &sh.data[j * BLOCK + wave * 64]);
        }
    }

    // --- Ballots -> per-(iter,wave) counts (LDS) + per-lane rank in regs.
    //     Runs while the DMA is in flight.
    u64 ltm = (1ULL << lane) - 1ULL;
    u32 preP[ITEMS / 4] = {0, 0};
#pragma unroll
    for (int j = 0; j < ITEMS; ++j) {
        bool valid = FULL || ((vmask >> j) & 1);
        int l = (packed >> (2 * j)) & 3;
        u64 m0 = __ballot(valid && l == 0);
        u64 m1 = __ballot(valid && l == 1);
        u64 m2 = __ballot(valid && l == 2);
        u64 m3 = __ballot(valid && l == 3);
        if (lane == 0) {
            sh.s_pre[j][wave][0] = (u32)__popcll(m0);
            sh.s_pre[j][wave][1] = (u32)__popcll(m1);
            sh.s_pre[j][wave][2] = (u32)__popcll(m2);
            sh.s_pre[j][wave][3] = (u32)__popcll(m3);
        }
        u64 mm = (l == 0) ? m0 : (l == 1) ? m1 : (l == 2) ? m2 : m3;
        preP[j >> 2] |= ((u32)__popcll(mm & ltm)) << (8 * (j & 3));
    }
    __syncthreads();  // counts visible; vmcnt(0) drain -> staged tile ready

    // --- Block scan: wave w owns class w; 32 entries in (j,wave) order,
    //     lanes 0..31 active (lanes >=32 must not read s_pre OOB).
    {
        int c = wave;
        u32 x = (lane < 32) ? sh.s_pre[lane >> 2][lane & 3][c] : 0u;
        u32 orig = x;
#pragma unroll
        for (int off = 1; off < 32; off <<= 1) {
            u32 v = (u32)__shfl_up((int)x, off, 64);
            if (lane >= off) x += v;
        }
        if (lane < 32) sh.s_pre[lane >> 2][lane & 3][c] = x - orig;
    }
    // (no barrier needed here: global_prefix's internal barriers cover the
    //  s_pre writes before any thread reads them in the process loop)

    global_prefix(sh, hist, nb, blockIdx.x);

    u32 sb0 = sh.s_bc[0], sb1 = sh.s_bc[1], sb2 = sh.s_bc[2], sb3 = sh.s_bc[3];
    u32 cb1 = sh.s_bc[4], cb2 = sh.s_bc[5], cb3 = sh.s_bc[6];

    // --- Process all 8 from LDS: adjust + scatter + loss.
    const float INV_M = 0.249999375f;  // 1/4.00001
    float loss = 0.f;
#pragma unroll
    for (int j = 0; j < ITEMS; ++j) {
        if (FULL || ((vmask >> j) & 1)) {
            float4 rr;
            if (FULL) {
                rr = sh.data[j * BLOCK + tid];       // ds_read_b128
            } else {
                rr = data[base + j * BLOCK + tid];   // guarded direct load
            }
            int l = (packed >> (2 * j)) & 3;
            u32 pre = (preP[j >> 2] >> (8 * (j & 3))) & 255u;
            u32 bb = (l == 0) ? sb0 : (l == 1) ? sb1 : (l == 2) ? sb2 : sb3;
            u32 dst = bb + sh.s_pre[j][wave][l] + pre;
            float v = (l == 0) ? rr.x : (l == 1) ? rr.y
                                     : (l == 2) ? rr.z : rr.w;
            float adj = (v > 0.f) ? (v * INV_M - 0.5f) : (v * 4.00001f - 0.5f);
            if (l == 0) rr.x = adj;
            else if (l == 1) rr.y = adj;
            else if (l == 2) rr.z = adj;
            else rr.w = adj;
            out_data[dst] = rr;
            float mx = fmaxf(fmaxf(rr.x, rr.y), fmaxf(rr.z, rr.w));
            float se = __expf(rr.x - mx) + __expf(rr.y - mx) +
                       __expf(rr.z - mx) + __expf(rr.w - mx);
            loss += (mx + __logf(se)) - adj;  // -log p_true
        }
    }

    // --- Fused analytic label write for this block's range (512 float4).
    {
        int t4base = base >> 2;
#pragma unroll
        for (int k = 0; k < 2; ++k) {
            int t4 = t4base + k * BLOCK + tid;
            int j0 = t4 * 4;
            if (FULL || j0 + 3 < N) {
                u32 j0u = (u32)j0;
                float4 rl;
                rl.x = (float)((j0u >= cb1) + (j0u >= cb2) + (j0u >= cb3));
                rl.y = (float)((j0u + 1 >= cb1) + (j0u + 1 >= cb2) + (j0u + 1 >= cb3));
                rl.z = (float)((j0u + 2 >= cb1) + (j0u + 2 >= cb2) + (j0u + 2 >= cb3));
                rl.w = (float)((j0u + 3 >= cb1) + (j0u + 3 >= cb2) + (j0u + 3 >= cb3));
                ((float4*)out_label)[t4] = rl;
            } else {
                for (int q = 0; q < 4; ++q) {
                    int jj = j0 + q;
                    if (jj >= 0 && jj < N) {
                        u32 ju = (u32)jj;
                        out_label[jj] =
                            (float)((ju >= cb1) + (ju >= cb2) + (ju >= cb3));
                    }
                }
            }
        }
    }

    // --- Block-reduce loss in double, one atomic per block; last block
    //     finalizes (proven r5/r6; saves the 3rd dispatch).
    double d = (double)loss;
#pragma unroll
    for (int off = 32; off > 0; off >>= 1) d += __shfl_down(d, off, 64);
    if (lane == 0) sh.s_w[wave] = d;
    __syncthreads();
    if (tid == 0) {
        atomicAdd(acc, sh.s_w[0] + sh.s_w[1] + sh.s_w[2] + sh.s_w[3]);
        __threadfence();
        u32 old = atomicAdd(done, 1u);
        if (old == (u32)(gridDim.x - 1)) {
            double tl = atomicAdd(acc, 0.0);  // coherent read of final sum
            *out_loss = (float)(tl / (double)N);
        }
    }
}

__global__ void __launch_bounds__(BLOCK)
sort_kernel(const float4* __restrict__ data, const u32* __restrict__ plab,
            int N, int nb, const u32* __restrict__ hist,
            float4* __restrict__ out_data, float* __restrict__ out_label,
            double* __restrict__ acc, u32* __restrict__ done,
            float* __restrict__ out_loss) {
    __shared__ SortShared sh;
    int base = blockIdx.x * CHUNK;
    if (base + CHUNK <= N) {
        sort_body<true>(sh, data, plab, N, nb, hist, out_data, out_label, acc,
                        done, out_loss);
    } else {
        sort_body<false>(sh, data, plab, N, nb, hist, out_data, out_label, acc,
                         done, out_loss);
    }
}

// ---------------------------------------------------------------------------
extern "C" void kernel_launch(void* const* d_in, const int* in_sizes, int n_in,
                              void* d_out, int out_size, void* d_ws,
                              size_t ws_size, hipStream_t stream) {
    const float* data = (const float*)d_in[0];
    const int* labels = (const int*)d_in[1];
    int N = in_sizes[1];
    int nb = (N + CHUNK - 1) / CHUNK;

    u32* hist = (u32*)d_ws;                     // nb*4 u32
    u32* plab = hist + (size_t)nb * 4;          // nb*BLOCK u32 (packed labels)
    double* acc =
        (double*)(((uintptr_t)(plab + (size_t)nb * BLOCK) + 15) &
                  ~(uintptr_t)15);
    u32* done = (u32*)(acc + 1);

    float* out = (float*)d_out;
    float* out_data = out;                   // N*4
    float* out_label = out + (size_t)N * 4;  // N
    float* out_loss = out + (size_t)N * 5;   // 1

    hist_kernel<<<nb, BLOCK, 0, stream>>>(labels, N, hist, plab, acc, done);
    sort_kernel<<<nb, BLOCK, 0, stream>>>((const float4*)data, plab, N, nb,
                                          hist, (float4*)out_data, out_label,
                                          acc, done, out_loss);
}

// Round 9
// 408.436 us; speedup vs baseline: 1.2301x; 1.2301x over previous
//
#include <hip/hip_runtime.h>
#include <math.h>
#include <stdint.h>

typedef unsigned int u32;
typedef unsigned long long u64;

#define BLOCK 256
#define ITEMS 16
#define CHUNK (BLOCK * ITEMS)  // 4096 elements per block

// ---------------------------------------------------------------------------
// Pass 1 (rank): reads labels ONCE; per-block ballots + LDS scan produce each
// element's within-block rank; writes u16 meta = rank(12b) | class(2b),
// thread-major (16 u16 = 32B contiguous per thread -> 2 uint4 stores) so
// pass 2 reads it back with 2 vector loads. Block class totals -> hist.
// Zero-inits loss accumulator + done ticket.
// ---------------------------------------------------------------------------
__global__ void __launch_bounds__(BLOCK)
rank_kernel(const int* __restrict__ labels, int N,
            u32* __restrict__ hist, u32* __restrict__ meta,
            double* __restrict__ acc, u32* __restrict__ done) {
    __shared__ u32 s_pre[ITEMS][4][4];  // [iter][wave][class]
    int tid = threadIdx.x;
    int lane = tid & 63;
    int wave = tid >> 6;
    int base = blockIdx.x * CHUNK;

    u32 vmask;
    {
        int rem = N - base - tid;
        if (rem >= (ITEMS - 1) * BLOCK + 1) vmask = 0xFFFFu;
        else {
            vmask = 0;
#pragma unroll
            for (int j = 0; j < ITEMS; ++j)
                vmask |= (u32)(j * BLOCK < rem) << j;
        }
    }

    // Ballots -> per-(iter,wave) counts (LDS) + per-lane prefix in regs.
    u64 ltm = (1ULL << lane) - 1ULL;
    u32 packed = 0;
    u32 preP[ITEMS / 4] = {0, 0, 0, 0};
#pragma unroll
    for (int j = 0; j < ITEMS; ++j) {
        bool valid = (vmask >> j) & 1;
        int l = valid ? labels[base + j * BLOCK + tid] : 0;
        packed |= (u32)l << (2 * j);
        u64 m0 = __ballot(valid && l == 0);
        u64 m1 = __ballot(valid && l == 1);
        u64 m2 = __ballot(valid && l == 2);
        u64 m3 = __ballot(valid && l == 3);
        if (lane == 0) {
            s_pre[j][wave][0] = (u32)__popcll(m0);
            s_pre[j][wave][1] = (u32)__popcll(m1);
            s_pre[j][wave][2] = (u32)__popcll(m2);
            s_pre[j][wave][3] = (u32)__popcll(m3);
        }
        u64 mm = (l == 0) ? m0 : (l == 1) ? m1 : (l == 2) ? m2 : m3;
        preP[j >> 2] |= ((u32)__popcll(mm & ltm)) << (8 * (j & 3));
    }
    __syncthreads();

    // Block scan: wave w owns class w; 64 entries in (j,wave) order.
    // lane63's inclusive sum = block total -> hist.
    {
        int c = wave;
        int e = lane;
        u32 x = s_pre[e >> 2][e & 3][c];
        u32 orig = x;
#pragma unroll
        for (int off = 1; off < 64; off <<= 1) {
            u32 v = (u32)__shfl_up((int)x, off, 64);
            if (lane >= off) x += v;
        }
        s_pre[e >> 2][e & 3][c] = x - orig;  // exclusive prefix in block
        if (lane == 63) hist[blockIdx.x * 4 + c] = x;  // block total
    }
    __syncthreads();

    // Pack per-element meta: rank-in-block (12b) | class (2b). Thread-major.
    u32 m[8] = {0, 0, 0, 0, 0, 0, 0, 0};
#pragma unroll
    for (int j = 0; j < ITEMS; ++j) {
        if ((vmask >> j) & 1) {
            int l = (packed >> (2 * j)) & 3;
            u32 pre = (preP[j >> 2] >> (8 * (j & 3))) & 255u;
            u32 rank = s_pre[j][wave][l] + pre;   // < 4096
            m[j >> 1] |= (rank | ((u32)l << 12)) << (16 * (j & 1));
        }
    }
    uint4* mp = (uint4*)meta + (size_t)(blockIdx.x * BLOCK + tid) * 2;
    mp[0] = make_uint4(m[0], m[1], m[2], m[3]);
    mp[1] = make_uint4(m[4], m[5], m[6], m[7]);

    if (blockIdx.x == 0 && tid == 0) { *acc = 0.0; *done = 0u; }
}

// ---------------------------------------------------------------------------
// Pass 2 (scatter): PURE STREAM — no ballots, no LDS scan, no plab decode.
// 2 uint4 meta loads + L2-hot global prefix + 16x{load,adjust,store,loss} +
// fused analytic label write + done-ticket loss finalize (no 3rd dispatch).
// LDS ~200B -> occupancy back to 8 blocks/CU.
// ---------------------------------------------------------------------------
struct ScatShared {
    u32 s_red[4][8];  // [wave][bef.xyzw, tot.xyzw]
    u32 s_bc[8];      // sb0..sb3, cb1..cb3
    double s_w[4];
};

__device__ __forceinline__ void
global_prefix(ScatShared& sh, const u32* __restrict__ hist, int nb, int myb) {
    int tid = threadIdx.x;
    int lane = tid & 63;
    int wave = tid >> 6;
    uint4 bef = make_uint4(0, 0, 0, 0), tot = make_uint4(0, 0, 0, 0);
    const uint4* h4 = (const uint4*)hist;
    for (int bb = tid; bb < nb; bb += BLOCK) {
        uint4 h = h4[bb];
        tot.x += h.x; tot.y += h.y; tot.z += h.z; tot.w += h.w;
        if (bb < myb) {
            bef.x += h.x; bef.y += h.y; bef.z += h.z; bef.w += h.w;
        }
    }
#pragma unroll
    for (int off = 32; off > 0; off >>= 1) {
        bef.x += (u32)__shfl_down((int)bef.x, off, 64);
        bef.y += (u32)__shfl_down((int)bef.y, off, 64);
        bef.z += (u32)__shfl_down((int)bef.z, off, 64);
        bef.w += (u32)__shfl_down((int)bef.w, off, 64);
        tot.x += (u32)__shfl_down((int)tot.x, off, 64);
        tot.y += (u32)__shfl_down((int)tot.y, off, 64);
        tot.z += (u32)__shfl_down((int)tot.z, off, 64);
        tot.w += (u32)__shfl_down((int)tot.w, off, 64);
    }
    if (lane == 0) {
        sh.s_red[wave][0] = bef.x; sh.s_red[wave][1] = bef.y;
        sh.s_red[wave][2] = bef.z; sh.s_red[wave][3] = bef.w;
        sh.s_red[wave][4] = tot.x; sh.s_red[wave][5] = tot.y;
        sh.s_red[wave][6] = tot.z; sh.s_red[wave][7] = tot.w;
    }
    __syncthreads();
    if (tid == 0) {
        u32 B0 = sh.s_red[0][0] + sh.s_red[1][0] + sh.s_red[2][0] + sh.s_red[3][0];
        u32 B1 = sh.s_red[0][1] + sh.s_red[1][1] + sh.s_red[2][1] + sh.s_red[3][1];
        u32 B2 = sh.s_red[0][2] + sh.s_red[1][2] + sh.s_red[2][2] + sh.s_red[3][2];
        u32 B3 = sh.s_red[0][3] + sh.s_red[1][3] + sh.s_red[2][3] + sh.s_red[3][3];
        u32 T0 = sh.s_red[0][4] + sh.s_red[1][4] + sh.s_red[2][4] + sh.s_red[3][4];
        u32 T1 = sh.s_red[0][5] + sh.s_red[1][5] + sh.s_red[2][5] + sh.s_red[3][5];
        u32 T2 = sh.s_red[0][6] + sh.s_red[1][6] + sh.s_red[2][6] + sh.s_red[3][6];
        u32 cb1 = T0, cb2 = T0 + T1, cb3 = T0 + T1 + T2;
        sh.s_bc[0] = B0;       sh.s_bc[1] = cb1 + B1;
        sh.s_bc[2] = cb2 + B2; sh.s_bc[3] = cb3 + B3;
        sh.s_bc[4] = cb1; sh.s_bc[5] = cb2; sh.s_bc[6] = cb3;
    }
    __syncthreads();
}

template <bool FULL>
__device__ __forceinline__ void
scatter_body(ScatShared& sh, const float4* __restrict__ data,
             const u32* __restrict__ meta, int N, int nb,
             const u32* __restrict__ hist, float4* __restrict__ out_data,
             float* __restrict__ out_label, double* __restrict__ acc,
             u32* __restrict__ done, float* __restrict__ out_loss) {
    int tid = threadIdx.x;
    int lane = tid & 63;
    int wave = tid >> 6;
    int base = blockIdx.x * CHUNK;

    // Meta: 32B/thread, issued first (retires under the prefix phase).
    const uint4* mp = (const uint4*)meta + (size_t)(blockIdx.x * BLOCK + tid) * 2;
    uint4 mA = mp[0];
    uint4 mB = mp[1];

    u32 vmask;
    if (FULL) {
        vmask = 0xFFFFu;
    } else {
        int rem = N - base - tid;
        vmask = 0;
#pragma unroll
        for (int j = 0; j < ITEMS; ++j)
            vmask |= (u32)(j * BLOCK < rem) << j;
    }

    global_prefix(sh, hist, nb, blockIdx.x);

    u32 sb0 = sh.s_bc[0], sb1 = sh.s_bc[1], sb2 = sh.s_bc[2], sb3 = sh.s_bc[3];
    u32 cb1 = sh.s_bc[4], cb2 = sh.s_bc[5], cb3 = sh.s_bc[6];

    u32 mm[8] = {mA.x, mA.y, mA.z, mA.w, mB.x, mB.y, mB.z, mB.w};

    // Pure stream: load -> add base -> adjust -> store -> loss.
    const float INV_M = 0.249999375f;  // 1/4.00001
    float loss = 0.f;
#pragma unroll
    for (int j = 0; j < ITEMS; ++j) {
        if (FULL || ((vmask >> j) & 1)) {
            u32 mv = (mm[j >> 1] >> (16 * (j & 1))) & 0xFFFFu;
            int l = (int)(mv >> 12);
            u32 rank = mv & 0xFFFu;
            float4 rr = data[base + j * BLOCK + tid];
            u32 bb = (l == 0) ? sb0 : (l == 1) ? sb1 : (l == 2) ? sb2 : sb3;
            u32 dst = bb + rank;
            float v = (l == 0) ? rr.x : (l == 1) ? rr.y
                                     : (l == 2) ? rr.z : rr.w;
            float adj = (v > 0.f) ? (v * INV_M - 0.5f) : (v * 4.00001f - 0.5f);
            if (l == 0) rr.x = adj;
            else if (l == 1) rr.y = adj;
            else if (l == 2) rr.z = adj;
            else rr.w = adj;
            out_data[dst] = rr;
            float mx = fmaxf(fmaxf(rr.x, rr.y), fmaxf(rr.z, rr.w));
            float se = __expf(rr.x - mx) + __expf(rr.y - mx) +
                       __expf(rr.z - mx) + __expf(rr.w - mx);
            loss += (mx + __logf(se)) - adj;  // -log p_true
        }
    }

    // Fused analytic label write for this block's range.
    {
        int t4base = base >> 2;
#pragma unroll
        for (int k = 0; k < 4; ++k) {
            int t4 = t4base + k * BLOCK + tid;
            int j0 = t4 * 4;
            if (FULL || j0 + 3 < N) {
                u32 j0u = (u32)j0;
                float4 rl;
                rl.x = (float)((j0u >= cb1) + (j0u >= cb2) + (j0u >= cb3));
                rl.y = (float)((j0u + 1 >= cb1) + (j0u + 1 >= cb2) + (j0u + 1 >= cb3));
                rl.z = (float)((j0u + 2 >= cb1) + (j0u + 2 >= cb2) + (j0u + 2 >= cb3));
                rl.w = (float)((j0u + 3 >= cb1) + (j0u + 3 >= cb2) + (j0u + 3 >= cb3));
                ((float4*)out_label)[t4] = rl;
            } else {
                for (int q = 0; q < 4; ++q) {
                    int jj = j0 + q;
                    if (jj >= 0 && jj < N) {
                        u32 ju = (u32)jj;
                        out_label[jj] =
                            (float)((ju >= cb1) + (ju >= cb2) + (ju >= cb3));
                    }
                }
            }
        }
    }

    // Block-reduce loss in double; last block finalizes (done-ticket).
    double d = (double)loss;
#pragma unroll
    for (int off = 32; off > 0; off >>= 1) d += __shfl_down(d, off, 64);
    if (lane == 0) sh.s_w[wave] = d;
    __syncthreads();
    if (tid == 0) {
        atomicAdd(acc, sh.s_w[0] + sh.s_w[1] + sh.s_w[2] + sh.s_w[3]);
        __threadfence();
        u32 old = atomicAdd(done, 1u);
        if (old == (u32)(gridDim.x - 1)) {
            double tl = atomicAdd(acc, 0.0);  // coherent read of final sum
            *out_loss = (float)(tl / (double)N);
        }
    }
}

__global__ void __launch_bounds__(BLOCK)
scatter_kernel(const float4* __restrict__ data, const u32* __restrict__ meta,
               int N, int nb, const u32* __restrict__ hist,
               float4* __restrict__ out_data, float* __restrict__ out_label,
               double* __restrict__ acc, u32* __restrict__ done,
               float* __restrict__ out_loss) {
    __shared__ ScatShared sh;
    int base = blockIdx.x * CHUNK;
    if (base + CHUNK <= N) {
        scatter_body<true>(sh, data, meta, N, nb, hist, out_data, out_label,
                           acc, done, out_loss);
    } else {
        scatter_body<false>(sh, data, meta, N, nb, hist, out_data, out_label,
                            acc, done, out_loss);
    }
}

// ---------------------------------------------------------------------------
extern "C" void kernel_launch(void* const* d_in, const int* in_sizes, int n_in,
                              void* d_out, int out_size, void* d_ws,
                              size_t ws_size, hipStream_t stream) {
    const float* data = (const float*)d_in[0];
    const int* labels = (const int*)d_in[1];
    int N = in_sizes[1];
    int nb = (N + CHUNK - 1) / CHUNK;

    u32* hist = (u32*)d_ws;  // nb*4 u32
    double* acc =
        (double*)(((uintptr_t)(hist + (size_t)nb * 4) + 15) & ~(uintptr_t)15);
    u32* done = (u32*)(acc + 1);
    // meta: nb*CHUNK u16, 16B-aligned, thread-major (2 uint4 per thread)
    u32* meta =
        (u32*)(((uintptr_t)(done + 1) + 15) & ~(uintptr_t)15);

    float* out = (float*)d_out;
    float* out_data = out;                   // N*4
    float* out_label = out + (size_t)N * 4;  // N
    float* out_loss = out + (size_t)N * 5;   // 1

    rank_kernel<<<nb, BLOCK, 0, stream>>>(labels, N, hist, meta, acc, done);
    scatter_kernel<<<nb, BLOCK, 0, stream>>>((const float4*)data, meta, N, nb,
                                             hist, (float4*)out_data,
                                             out_label, acc, done, out_loss);
}